// Round 1
// baseline (579.386 us; speedup 1.0000x reference)
//
#include <hip/hip_runtime.h>

#define NCOEF 18
#define TILE 256          // rows per block tile == blockDim.x
#define GRID1 2048        // blocks for the partial kernel (grid-stride over tiles)

// Kernel 1: per-block partial sums of (tmp-y)^2 and (tmp-B_tl)^2.
// Stages each 256-row tile into LDS with coalesced float4 loads of the flat
// arrays (tile byte offsets are 16B-aligned: 256*19*4 = 19456, 256*18*4 = 18432),
// then each thread computes one row from LDS.
__global__ __launch_bounds__(256) void loss_partial_kernel(
    const float* __restrict__ mo,   // (N, 19) row-major
    const float* __restrict__ y,    // (N, 1)
    const float* __restrict__ A,    // (N, 18) row-major
    const float* __restrict__ Btl,  // (N, 1)
    const float* __restrict__ beta, // (18,)
    float2* __restrict__ partial,   // (gridDim.x,) partial sums
    int N, int numTiles)
{
    __shared__ __align__(16) float s_mo[TILE * 19];
    __shared__ __align__(16) float s_a [TILE * 18];
    __shared__ __align__(16) float s_y [TILE];
    __shared__ __align__(16) float s_b [TILE];
    __shared__ float2 s_red[TILE / 64];

    const int tid = threadIdx.x;

    // beta is tiny + uniform: registers (compiler emits scalar loads)
    float bcoef[NCOEF];
#pragma unroll
    for (int j = 0; j < NCOEF; ++j) bcoef[j] = beta[j];

    float s1 = 0.0f, s2 = 0.0f;

    for (int t = blockIdx.x; t < numTiles; t += gridDim.x) {
        const int base = t * TILE;
        const int rows = min(TILE, N - base);

        // ---- stage model_output tile (rows*19 floats, coalesced float4) ----
        {
            const int nf = rows * 19;
            const float4* src = reinterpret_cast<const float4*>(mo + (size_t)base * 19);
            float4* dst = reinterpret_cast<float4*>(s_mo);
            for (int i = tid; i < (nf >> 2); i += TILE) dst[i] = src[i];
            for (int i = (nf & ~3) + tid; i < nf; i += TILE)
                s_mo[i] = mo[(size_t)base * 19 + i];
        }
        // ---- stage A tile (rows*18 floats) ----
        {
            const int nf = rows * 18;
            const float4* src = reinterpret_cast<const float4*>(A + (size_t)base * 18);
            float4* dst = reinterpret_cast<float4*>(s_a);
            for (int i = tid; i < (nf >> 2); i += TILE) dst[i] = src[i];
            for (int i = (nf & ~3) + tid; i < nf; i += TILE)
                s_a[i] = A[(size_t)base * 18 + i];
        }
        // ---- stage y, B_tl tiles ----
        {
            const float4* srcy = reinterpret_cast<const float4*>(y + base);
            const float4* srcb = reinterpret_cast<const float4*>(Btl + base);
            float4* dsty = reinterpret_cast<float4*>(s_y);
            float4* dstb = reinterpret_cast<float4*>(s_b);
            for (int i = tid; i < (rows >> 2); i += TILE) { dsty[i] = srcy[i]; dstb[i] = srcb[i]; }
            for (int i = (rows & ~3) + tid; i < rows; i += TILE) {
                s_y[i] = y[base + i];
                s_b[i] = Btl[base + i];
            }
        }
        __syncthreads();

        // ---- compute: one row per thread ----
        if (tid < rows) {
            float tmp = s_mo[tid * 19 + NCOEF];     // d
#pragma unroll
            for (int j = 0; j < NCOEF; ++j)
                tmp = fmaf(s_a[tid * 18 + j], bcoef[j] + s_mo[tid * 19 + j], tmp);
            const float e1 = tmp - s_y[tid];
            const float e2 = tmp - s_b[tid];
            s1 = fmaf(e1, e1, s1);
            s2 = fmaf(e2, e2, s2);
        }
        __syncthreads();   // LDS reused next iteration
    }

    // ---- wave (64-lane) reduction, then cross-wave via LDS ----
#pragma unroll
    for (int off = 32; off > 0; off >>= 1) {
        s1 += __shfl_down(s1, off);
        s2 += __shfl_down(s2, off);
    }
    if ((tid & 63) == 0) s_red[tid >> 6] = make_float2(s1, s2);
    __syncthreads();
    if (tid == 0) {
        float a1 = 0.0f, a2 = 0.0f;
#pragma unroll
        for (int w = 0; w < TILE / 64; ++w) { a1 += s_red[w].x; a2 += s_red[w].y; }
        partial[blockIdx.x] = make_float2(a1, a2);
    }
}

// Kernel 2: reduce block partials, write (S1 + LAMBDA_PHY*S2) / N  (lambda = 1)
__global__ __launch_bounds__(256) void loss_final_kernel(
    const float2* __restrict__ partial, int nPart,
    float* __restrict__ out, float invN)
{
    __shared__ float2 s_red[4];
    float s1 = 0.0f, s2 = 0.0f;
    for (int i = threadIdx.x; i < nPart; i += 256) {
        const float2 p = partial[i];
        s1 += p.x; s2 += p.y;
    }
#pragma unroll
    for (int off = 32; off > 0; off >>= 1) {
        s1 += __shfl_down(s1, off);
        s2 += __shfl_down(s2, off);
    }
    if ((threadIdx.x & 63) == 0) s_red[threadIdx.x >> 6] = make_float2(s1, s2);
    __syncthreads();
    if (threadIdx.x == 0) {
        float a1 = 0.0f, a2 = 0.0f;
#pragma unroll
        for (int w = 0; w < 4; ++w) { a1 += s_red[w].x; a2 += s_red[w].y; }
        out[0] = (a1 + a2) * invN;
    }
}

extern "C" void kernel_launch(void* const* d_in, const int* in_sizes, int n_in,
                              void* d_out, int out_size, void* d_ws, size_t ws_size,
                              hipStream_t stream) {
    const float* mo   = (const float*)d_in[0];  // model_output (N, 19)
    const float* y    = (const float*)d_in[1];  // y (N, 1)
    const float* A    = (const float*)d_in[2];  // A (N, 18)
    const float* Btl  = (const float*)d_in[3];  // B_tl (N, 1)
    const float* beta = (const float*)d_in[4];  // beta_TL (18,)
    float* out = (float*)d_out;

    const int N = in_sizes[1];                  // y has N elements
    const int numTiles = (N + TILE - 1) / TILE;
    const int g1 = numTiles < GRID1 ? numTiles : GRID1;

    float2* partial = (float2*)d_ws;            // g1 * 8 bytes, written before read

    loss_partial_kernel<<<g1, TILE, 0, stream>>>(mo, y, A, Btl, beta, partial, N, numTiles);
    loss_final_kernel<<<1, 256, 0, stream>>>(partial, g1, out, 1.0f / (float)N);
}

// Round 2
// 578.447 us; speedup vs baseline: 1.0016x; 1.0016x over previous
//
#include <hip/hip_runtime.h>

#define NCOEF 18
#define TILE 256          // rows per tile == blockDim.x
#define NWAVES 4
#define GRID1 2048

typedef unsigned int u32;

// Fire-and-forget 16B global->LDS DMA. LDS dest is wave-uniform base + lane*16
// (HW adds the lane offset); global src is per-lane. Our staging is exactly
// linear, which is the one layout this instruction supports (m104/m173).
__device__ __forceinline__ void gload_lds16(const void* g, void* l) {
    __builtin_amdgcn_global_load_lds(
        (const __attribute__((address_space(1))) u32*)g,
        (__attribute__((address_space(3))) u32*)l,
        16, 0, 0);
}

// Kernel 1: per-block partial sums of (tmp-y)^2 and (tmp-B_tl)^2.
// mo tile: 256 rows * 19 f32 = 19456 B = 19 chunks of 1024 B (one chunk = one
// wave-wide 16B/lane DMA). A tile: 256*18*4 = 18432 B = 18 chunks.
// y/B_tl are stride-4 coalesced already -> read direct from global.
__global__ __launch_bounds__(256, 4) void loss_partial_kernel(
    const float* __restrict__ mo,   // (N,19)
    const float* __restrict__ y,    // (N,1)
    const float* __restrict__ A,    // (N,18)
    const float* __restrict__ Btl,  // (N,1)
    const float* __restrict__ beta, // (18,)
    float2* __restrict__ partial,
    int numFullTiles, int N)
{
    __shared__ __align__(16) float s_mo[TILE * 19];
    __shared__ __align__(16) float s_a [TILE * 18];
    __shared__ float2 s_red[NWAVES];

    const int tid  = threadIdx.x;
    const int lane = tid & 63;
    const int wave = tid >> 6;

    float bc[NCOEF];
#pragma unroll
    for (int j = 0; j < NCOEF; ++j) bc[j] = beta[j];

    float s1 = 0.0f, s2 = 0.0f;

    for (int t = blockIdx.x; t < numFullTiles; t += gridDim.x) {
        const size_t R0 = (size_t)t * TILE;

        const char* mo_src = (const char*)(mo + R0 * 19) + lane * 16;
        const char* a_src  = (const char*)(A  + R0 * 18) + lane * 16;

        // issue all chunks back-to-back; no waits between (vmcnt queues them)
#pragma unroll
        for (int c = wave; c < 19; c += NWAVES)
            gload_lds16(mo_src + c * 1024, (char*)s_mo + c * 1024);
#pragma unroll
        for (int c = wave; c < 18; c += NWAVES)
            gload_lds16(a_src + c * 1024, (char*)s_a + c * 1024);

        asm volatile("s_waitcnt vmcnt(0)" ::: "memory");
        __syncthreads();

        // one row per thread from LDS
        float tmp = s_mo[tid * 19 + NCOEF];   // d
#pragma unroll
        for (int j = 0; j < NCOEF; ++j)
            tmp = fmaf(s_a[tid * 18 + j], bc[j] + s_mo[tid * 19 + j], tmp);

        const float yv = y[R0 + tid];
        const float bv = Btl[R0 + tid];
        const float e1 = tmp - yv;
        const float e2 = tmp - bv;
        s1 = fmaf(e1, e1, s1);
        s2 = fmaf(e2, e2, s2);

        __syncthreads();   // all reads done before next tile's DMA lands
    }

    // tail rows (none when N % 256 == 0; N = 4,000,000 = 15625*256 exactly)
    const int rem = N - numFullTiles * TILE;
    if (rem > 0 && blockIdx.x == gridDim.x - 1 && tid < rem) {
        const size_t r = (size_t)numFullTiles * TILE + tid;
        float tmp = mo[r * 19 + NCOEF];
#pragma unroll
        for (int j = 0; j < NCOEF; ++j)
            tmp = fmaf(A[r * 18 + j], bc[j] + mo[r * 19 + j], tmp);
        const float e1 = tmp - y[r];
        const float e2 = tmp - Btl[r];
        s1 = fmaf(e1, e1, s1);
        s2 = fmaf(e2, e2, s2);
    }

    // wave reduce (64 lanes) then cross-wave via LDS
#pragma unroll
    for (int off = 32; off > 0; off >>= 1) {
        s1 += __shfl_down(s1, off);
        s2 += __shfl_down(s2, off);
    }
    if (lane == 0) s_red[wave] = make_float2(s1, s2);
    __syncthreads();
    if (tid == 0) {
        float a1 = 0.0f, a2 = 0.0f;
#pragma unroll
        for (int w = 0; w < NWAVES; ++w) { a1 += s_red[w].x; a2 += s_red[w].y; }
        partial[blockIdx.x] = make_float2(a1, a2);
    }
}

// Kernel 2: reduce block partials -> (S1 + S2) / N  (lambda = 1)
__global__ __launch_bounds__(256) void loss_final_kernel(
    const float2* __restrict__ partial, int nPart,
    float* __restrict__ out, float invN)
{
    __shared__ float2 s_red[4];
    float s1 = 0.0f, s2 = 0.0f;
    for (int i = threadIdx.x; i < nPart; i += 256) {
        const float2 p = partial[i];
        s1 += p.x; s2 += p.y;
    }
#pragma unroll
    for (int off = 32; off > 0; off >>= 1) {
        s1 += __shfl_down(s1, off);
        s2 += __shfl_down(s2, off);
    }
    if ((threadIdx.x & 63) == 0) s_red[threadIdx.x >> 6] = make_float2(s1, s2);
    __syncthreads();
    if (threadIdx.x == 0) {
        float a1 = 0.0f, a2 = 0.0f;
#pragma unroll
        for (int w = 0; w < 4; ++w) { a1 += s_red[w].x; a2 += s_red[w].y; }
        out[0] = (a1 + a2) * invN;
    }
}

extern "C" void kernel_launch(void* const* d_in, const int* in_sizes, int n_in,
                              void* d_out, int out_size, void* d_ws, size_t ws_size,
                              hipStream_t stream) {
    const float* mo   = (const float*)d_in[0];
    const float* y    = (const float*)d_in[1];
    const float* A    = (const float*)d_in[2];
    const float* Btl  = (const float*)d_in[3];
    const float* beta = (const float*)d_in[4];
    float* out = (float*)d_out;

    const int N = in_sizes[1];                 // y has N elements
    const int numFullTiles = N / TILE;
    int g1 = numFullTiles < GRID1 ? numFullTiles : GRID1;
    if (g1 < 1) g1 = 1;

    float2* partial = (float2*)d_ws;           // g1*8 bytes, written before read

    loss_partial_kernel<<<g1, TILE, 0, stream>>>(mo, y, A, Btl, beta, partial,
                                                 numFullTiles, N);
    loss_final_kernel<<<1, 256, 0, stream>>>(partial, g1, out, 1.0f / (float)N);
}